// Round 12
// baseline (120.904 us; speedup 1.0000x reference)
//
#include <hip/hip_runtime.h>

#define HW_  4096
#define DQK  131072     // 32*4096 per batch (q or k)
#define DV   1048576    // 256*4096 per batch

using bf16x8 = __attribute__((ext_vector_type(8))) __bf16;
using f32x4  = __attribute__((ext_vector_type(4))) float;
using u16x8  = __attribute__((ext_vector_type(8))) unsigned short;

static __device__ __forceinline__ unsigned short f2bf(float f) {
    union { float f; unsigned u; } v; v.f = f;
    unsigned r = v.u + 0x7FFFu + ((v.u >> 16) & 1u);
    return (unsigned short)(r >> 16);
}

// ---------------- qk GEMM, split-bf16, NO LDS, no barriers; A-frags packed in-register
// straight from wq/wk (L2-hot). Also resets the scores ticket counter each launch.
// QF/KF stored FLAT: b*DQK + nblk*2048 + slot*256 + lane*4 + i.
__global__ __launch_bounds__(256) void k_gemm_qk(const float* __restrict__ wq,
                                                 const float* __restrict__ wk,
                                                 const float* __restrict__ x,
                                                 const float* __restrict__ bq, const float* __restrict__ bk,
                                                 float* __restrict__ QF, float* __restrict__ KF,
                                                 unsigned int* __restrict__ ticket) {
    if (blockIdx.x == 0 && blockIdx.y == 0 && threadIdx.x == 0) *ticket = 0u;
    int b  = blockIdx.y;
    int n0 = blockIdx.x * 64;
    int t = threadIdx.x;
    int lane = t & 63, wid = t >> 6;
    int wm = wid & 1, wn = wid >> 1;
    int lr = lane & 15, kg = lane >> 4;

    const float* xb = x + (size_t)b * DV;
    const float* wsrc = (wm == 0) ? wq : wk;

    f32x4 acc[2][2];
    for (int mi = 0; mi < 2; mi++)
        for (int ni = 0; ni < 2; ni++) acc[mi][ni] = (f32x4){0.f, 0.f, 0.f, 0.f};

    for (int kk = 0; kk < 8; kk++) {
        bf16x8 ah[2], al[2];
        for (int mi = 0; mi < 2; mi++) {
            const float* wp = wsrc + (size_t)(mi * 16 + lr) * 256 + kk * 32 + kg * 8;
            f32x4 w0 = *(const f32x4*)(wp);
            f32x4 w1 = *(const f32x4*)(wp + 4);
            #pragma unroll
            for (int j = 0; j < 4; j++) {
                __bf16 h0 = (__bf16)w0[j];
                ah[mi][j] = h0;
                al[mi][j] = (__bf16)(w0[j] - (float)h0);
                __bf16 h1 = (__bf16)w1[j];
                ah[mi][j + 4] = h1;
                al[mi][j + 4] = (__bf16)(w1[j] - (float)h1);
            }
        }
        bf16x8 bh[2], bl[2];
        int cbase = kk * 32 + kg * 8;
        for (int ni = 0; ni < 2; ni++) {
            const float* xp = xb + (size_t)cbase * HW_ + n0 + wn * 32 + ni * 16 + lr;
            #pragma unroll
            for (int j = 0; j < 8; j++) {
                float v = xp[(size_t)j * HW_];
                __bf16 h = (__bf16)v;
                bh[ni][j] = h;
                bl[ni][j] = (__bf16)(v - (float)h);
            }
        }
        for (int mi = 0; mi < 2; mi++)
            for (int ni = 0; ni < 2; ni++) {
                acc[mi][ni] = __builtin_amdgcn_mfma_f32_16x16x32_bf16(ah[mi], bh[ni], acc[mi][ni], 0, 0, 0);
                acc[mi][ni] = __builtin_amdgcn_mfma_f32_16x16x32_bf16(ah[mi], bl[ni], acc[mi][ni], 0, 0, 0);
                acc[mi][ni] = __builtin_amdgcn_mfma_f32_16x16x32_bf16(al[mi], bh[ni], acc[mi][ni], 0, 0, 0);
            }
    }

    float* dst = (wm == 0) ? QF : KF;
    const float* bias = (wm == 0) ? bq : bk;
    size_t base = (size_t)b * DQK + (size_t)blockIdx.x * 2048;
    for (int mi = 0; mi < 2; mi++) {
        f32x4 bvv = *(const f32x4*)(bias + mi * 16 + kg * 4);
        for (int ni = 0; ni < 2; ni++) {
            int slot = (wn * 2 + ni) * 2 + mi;
            f32x4 v = acc[mi][ni] + bvv;
            *(f32x4*)(dst + base + slot * 256 + lane * 4) = v;
        }
    }
}

// ---------------- scores + last-block softmax. 256 blocks; each owns a flat 512-slice.
// Last block (device-scope ticket) reduces Sp, does softmax+gamma -> Mm[0..255] + rowsum[256..271].
__global__ __launch_bounds__(256) void k_scores3(const float* __restrict__ QF, const float* __restrict__ KF,
                                                 const float* __restrict__ gamma,
                                                 float* __restrict__ Sp, float* __restrict__ Mm,
                                                 unsigned int* __restrict__ ticket) {
    __shared__ float Ql[16][520], Kl[16][520];
    __shared__ unsigned int isLast;
    int s = blockIdx.x;
    size_t off = (size_t)s * 512;
    int t = threadIdx.x;
    for (int b = 0; b < 16; b++) {
        const float* qs = QF + (size_t)b * DQK + off;
        const float* ks = KF + (size_t)b * DQK + off;
        Ql[b][t]       = qs[t];
        Ql[b][t + 256] = qs[t + 256];
        Kl[b][t]       = ks[t];
        Kl[b][t + 256] = ks[t + 256];
    }
    __syncthreads();
    {
        int p = t >> 1, h = t & 1;
        int b = p >> 3, j = p & 7;
        int hb = b >> 2, wb = b & 3;
        int bp = (j < 4) ? (j * 4 + wb) : (hb * 4 + (j - 4));
        const f32x4* q4 = (const f32x4*)&Ql[b][h * 256];
        const f32x4* k4 = (const f32x4*)&Kl[bp][h * 256];
        f32x4 a4 = (f32x4){0.f, 0.f, 0.f, 0.f};
        for (int i = 0; i < 64; i++) a4 += q4[i] * k4[i];
        float sres = a4[0] + a4[1] + a4[2] + a4[3];
        sres += __shfl_xor(sres, 1);
        if (h == 0) Sp[(size_t)p * 256 + s] = sres;
    }
    __threadfence();                                  // release Sp writes (device scope)
    if (t == 0) isLast = (atomicAdd(ticket, 1u) == 255u) ? 1u : 0u;
    __syncthreads();
    if (isLast) {
        __threadfence();                              // acquire other blocks' Sp
        __shared__ float SS[128];
        if (t < 128) {
            const f32x4* s4 = (const f32x4*)(Sp + (size_t)t * 256);
            f32x4 a = (f32x4){0.f, 0.f, 0.f, 0.f};
            for (int i = 0; i < 64; i++) a += s4[i];
            SS[t] = a[0] + a[1] + a[2] + a[3];
        }
        __syncthreads();
        if (t < 16) {
            int b = t, h = b >> 2, w = b & 3;
            float e[8];
            for (int j = 0; j < 8; j++) e[j] = SS[b * 8 + j];
            e[h] = -INFINITY;
            float mx = e[0];
            for (int j = 1; j < 8; j++) mx = fmaxf(mx, e[j]);
            float aa[8], sum = 0.f;
            for (int j = 0; j < 8; j++) { aa[j] = expf(e[j] - mx); sum += aa[j]; }
            float inv = 1.0f / sum;
            float g = gamma[0];
            float row[16];
            for (int c = 0; c < 16; c++) row[c] = 0.f;
            for (int gg = 0; gg < 4; gg++) if (gg != h) row[gg * 4 + w] += aa[gg] * inv;
            for (int gg = 0; gg < 4; gg++) row[h * 4 + gg] += aa[4 + gg] * inv;
            for (int c = 0; c < 16; c++) Mm[b * 16 + c] = row[c] * g;
            Mm[256 + b] = g;
        }
    }
}

// ---------------- mix + transpose + convert -> pre-fragmented Xm; blocks 1024+ pack WvF.
// Xm addr(b,p,c) = b*DV + (p>>4)*4096 + (c>>3)*128 + (p&15)*8 + (c&7).
__global__ __launch_bounds__(256) void k_mix(const float* __restrict__ Mm, const float* __restrict__ x,
                                             const float* __restrict__ wv,
                                             unsigned short* __restrict__ Xm,
                                             unsigned short* __restrict__ WvF) {
    int bid = blockIdx.x;
    int t = threadIdx.x;
    if (bid >= 1024) {                                // 8 pack blocks: wv -> WvF frag layout
        int chunk = (bid - 1024) * 16384;
        for (int i = t; i < 16384; i += 256) {
            int ii = chunk + i;
            int mt = ii >> 12, kt = (ii >> 7) & 31, lr = (ii >> 3) & 15, j = ii & 7;
            WvF[ii] = f2bf(wv[(mt * 16 + lr) * 256 + kt * 8 + j]);
        }
        return;
    }
    __shared__ float Ms[256];
    __shared__ __align__(16) unsigned short T[16][32][40];
    int p0 = (bid & 127) * 32, c0 = (bid >> 7) * 32;
    Ms[t] = Mm[t];

    int c_l = t >> 3, p4 = t & 7;
    f32x4 in4[16];
    for (int bp = 0; bp < 16; bp++)
        in4[bp] = *(const f32x4*)(x + (size_t)bp * DV + (size_t)(c0 + c_l) * HW_ + p0 + p4 * 4);
    __syncthreads();
    for (int b = 0; b < 16; b++) {
        int h = b >> 2, w = b & 3;
        f32x4 acc = (f32x4){0.f, 0.f, 0.f, 0.f};
        #pragma unroll
        for (int g = 0; g < 4; g++) {
            if (g != h) acc += Ms[b * 16 + g * 4 + w] * in4[g * 4 + w];
            acc += Ms[b * 16 + h * 4 + g] * in4[h * 4 + g];
        }
        for (int e = 0; e < 4; e++) T[b][p4 * 4 + e][c_l] = f2bf(acc[e]);
    }
    __syncthreads();
    int p_l = t & 31, co = (t >> 5) & 3, bh = t >> 7;
    int p = p0 + p_l;
    int c = c0 + co * 8;
    size_t dst = (size_t)(p >> 4) * 4096 + (size_t)(c >> 3) * 128 + (p & 15) * 8;
    #pragma unroll
    for (int bi = 0; bi < 8; bi++) {
        int b = bh * 8 + bi;
        u16x8 v = *(const u16x8*)&T[b][p_l][co * 8];
        *(u16x8*)(Xm + (size_t)b * DV + dst) = v;
    }
}

// ---------------- v GEMM + bias + residual: NO-LDS k-loop; LDS-staged coalesced epilogue
// with nontemporal out stores (r11-validated).
__global__ __launch_bounds__(512) void k_gemm_v_res(const unsigned short* __restrict__ WvF,
                                                    const unsigned short* __restrict__ XmF,
                                                    const float* __restrict__ bv,
                                                    const float* __restrict__ MmRs,
                                                    const float* __restrict__ x,
                                                    float* __restrict__ out) {
    __shared__ __align__(16) float LD[256][68];
    int b  = blockIdx.y;
    int n0 = blockIdx.x * 64;
    int t = threadIdx.x;
    int lane = t & 63, wid = t >> 6;
    int wm = wid >> 1, wn = wid & 1;
    int lr = lane & 15, kg = lane >> 4;

    const unsigned short* Bb = XmF + (size_t)b * DV + (size_t)(blockIdx.x * 4 + wn * 2) * 4096 + lane * 8;
    const unsigned short* Ab = WvF + (size_t)(wm * 4) * 4096 + lane * 8;

    bf16x8 bfr[8][2];
    #pragma unroll
    for (int kk = 0; kk < 8; kk++)
        #pragma unroll
        for (int ni = 0; ni < 2; ni++)
            bfr[kk][ni] = *(const bf16x8*)(Bb + (size_t)ni * 4096 + kk * 512);

    f32x4 acc[4][2];
    #pragma unroll
    for (int mi = 0; mi < 4; mi++)
        for (int ni = 0; ni < 2; ni++) acc[mi][ni] = (f32x4){0.f, 0.f, 0.f, 0.f};

    bf16x8 a[4], an[4];
    #pragma unroll
    for (int mi = 0; mi < 4; mi++) a[mi] = *(const bf16x8*)(Ab + (size_t)mi * 4096);
    #pragma unroll
    for (int kk = 0; kk < 8; kk++) {
        if (kk < 7) {
            #pragma unroll
            for (int mi = 0; mi < 4; mi++)
                an[mi] = *(const bf16x8*)(Ab + (size_t)mi * 4096 + (kk + 1) * 512);
        }
        #pragma unroll
        for (int mi = 0; mi < 4; mi++)
            #pragma unroll
            for (int ni = 0; ni < 2; ni++)
                acc[mi][ni] = __builtin_amdgcn_mfma_f32_16x16x32_bf16(a[mi], bfr[kk][ni], acc[mi][ni], 0, 0, 0);
        #pragma unroll
        for (int mi = 0; mi < 4; mi++) a[mi] = an[mi];
    }

    float rs = MmRs[256 + b];
    #pragma unroll
    for (int mi = 0; mi < 4; mi++) {
        int mrow0 = wm * 64 + mi * 16 + kg * 4;
        f32x4 bvv = *(const f32x4*)(bv + mrow0);
        #pragma unroll
        for (int ni = 0; ni < 2; ni++) {
            f32x4 mo = acc[mi][ni] + rs * bvv;
            int ncol = wn * 32 + ni * 16 + lr;
            #pragma unroll
            for (int i = 0; i < 4; i++) LD[mrow0 + i][ncol] = mo[i];
        }
    }
    __syncthreads();
    #pragma unroll
    for (int ps = 0; ps < 8; ps++) {
        int row = wid * 32 + ps * 4 + (lane >> 4);
        int nc  = (lane & 15) * 4;
        f32x4 o = *(const f32x4*)&LD[row][nc];
        size_t g = (size_t)b * DV + (size_t)row * HW_ + n0 + nc;
        f32x4 rr = *(const f32x4*)(x + g);
        __builtin_nontemporal_store(o + rr, (f32x4*)(out + g));
    }
}

extern "C" void kernel_launch(void* const* d_in, const int* in_sizes, int n_in,
                              void* d_out, int out_size, void* d_ws, size_t ws_size,
                              hipStream_t stream) {
    (void)in_sizes; (void)n_in; (void)out_size; (void)ws_size;
    const float* x     = (const float*)d_in[0];
    const float* wq    = (const float*)d_in[1];
    const float* bq    = (const float*)d_in[2];
    const float* wk    = (const float*)d_in[3];
    const float* bk    = (const float*)d_in[4];
    const float* wv    = (const float*)d_in[5];
    const float* bv    = (const float*)d_in[6];
    const float* gamma = (const float*)d_in[7];

    char* ws = (char*)d_ws;
    // ws layout: WvF 131072 | QF 8388608 | KF 8388608 | Mm 1088 | ticket 4 | Xm 33554432
    // Sp aliases Xm (consumed by scores3's winner before mix writes Xm).
    unsigned short* WvF    = (unsigned short*)(ws + 0);
    float*          QF     = (float*)(ws + 131072);
    float*          KF     = (float*)(ws + 8519680);
    float*          Mm     = (float*)(ws + 16908288);
    unsigned int*   ticket = (unsigned int*)(ws + 16909376);
    unsigned short* Xm     = (unsigned short*)(ws + 16910336);   // +33554432 = 50464768 total
    float*          Sp     = (float*)(ws + 16910336);            // aliases Xm
    float*          vo     = (float*)d_out;

    k_gemm_qk    <<<dim3(64, 16), 256, 0, stream>>>(wq, wk, x, bq, bk, QF, KF, ticket);
    k_scores3    <<<256, 256, 0, stream>>>(QF, KF, gamma, Sp, Mm, ticket);
    k_mix        <<<1032, 256, 0, stream>>>(Mm, x, wv, Xm, WvF);
    k_gemm_v_res <<<dim3(64, 16), 512, 0, stream>>>(WvF, Xm, bv, Mm, x, vo);
}

// Round 13
// 95.742 us; speedup vs baseline: 1.2628x; 1.2628x over previous
//
#include <hip/hip_runtime.h>

#define HW_  4096
#define DQK  131072     // 32*4096 per batch (q or k)
#define DV   1048576    // 256*4096 per batch

using bf16x8 = __attribute__((ext_vector_type(8))) __bf16;
using f32x4  = __attribute__((ext_vector_type(4))) float;
using u16x8  = __attribute__((ext_vector_type(8))) unsigned short;

static __device__ __forceinline__ unsigned short f2bf(float f) {
    union { float f; unsigned u; } v; v.f = f;
    unsigned r = v.u + 0x7FFFu + ((v.u >> 16) & 1u);
    return (unsigned short)(r >> 16);
}

// ---------------- qk GEMM, split-bf16, NO LDS, no barriers; A-frags packed in-register
// straight from wq/wk (L2-hot). QF/KF stored FLAT: b*DQK + nblk*2048 + slot*256 + lane*4 + i.
__global__ __launch_bounds__(256) void k_gemm_qk(const float* __restrict__ wq,
                                                 const float* __restrict__ wk,
                                                 const float* __restrict__ x,
                                                 const float* __restrict__ bq, const float* __restrict__ bk,
                                                 float* __restrict__ QF, float* __restrict__ KF) {
    int b  = blockIdx.y;
    int n0 = blockIdx.x * 64;
    int t = threadIdx.x;
    int lane = t & 63, wid = t >> 6;
    int wm = wid & 1, wn = wid >> 1;
    int lr = lane & 15, kg = lane >> 4;

    const float* xb = x + (size_t)b * DV;
    const float* wsrc = (wm == 0) ? wq : wk;

    f32x4 acc[2][2];
    for (int mi = 0; mi < 2; mi++)
        for (int ni = 0; ni < 2; ni++) acc[mi][ni] = (f32x4){0.f, 0.f, 0.f, 0.f};

    for (int kk = 0; kk < 8; kk++) {
        bf16x8 ah[2], al[2];
        for (int mi = 0; mi < 2; mi++) {
            const float* wp = wsrc + (size_t)(mi * 16 + lr) * 256 + kk * 32 + kg * 8;
            f32x4 w0 = *(const f32x4*)(wp);
            f32x4 w1 = *(const f32x4*)(wp + 4);
            #pragma unroll
            for (int j = 0; j < 4; j++) {
                __bf16 h0 = (__bf16)w0[j];
                ah[mi][j] = h0;
                al[mi][j] = (__bf16)(w0[j] - (float)h0);
                __bf16 h1 = (__bf16)w1[j];
                ah[mi][j + 4] = h1;
                al[mi][j + 4] = (__bf16)(w1[j] - (float)h1);
            }
        }
        bf16x8 bh[2], bl[2];
        int cbase = kk * 32 + kg * 8;
        for (int ni = 0; ni < 2; ni++) {
            const float* xp = xb + (size_t)cbase * HW_ + n0 + wn * 32 + ni * 16 + lr;
            #pragma unroll
            for (int j = 0; j < 8; j++) {
                float v = xp[(size_t)j * HW_];
                __bf16 h = (__bf16)v;
                bh[ni][j] = h;
                bl[ni][j] = (__bf16)(v - (float)h);
            }
        }
        for (int mi = 0; mi < 2; mi++)
            for (int ni = 0; ni < 2; ni++) {
                acc[mi][ni] = __builtin_amdgcn_mfma_f32_16x16x32_bf16(ah[mi], bh[ni], acc[mi][ni], 0, 0, 0);
                acc[mi][ni] = __builtin_amdgcn_mfma_f32_16x16x32_bf16(ah[mi], bl[ni], acc[mi][ni], 0, 0, 0);
                acc[mi][ni] = __builtin_amdgcn_mfma_f32_16x16x32_bf16(al[mi], bh[ni], acc[mi][ni], 0, 0, 0);
            }
    }

    float* dst = (wm == 0) ? QF : KF;
    const float* bias = (wm == 0) ? bq : bk;
    size_t base = (size_t)b * DQK + (size_t)blockIdx.x * 2048;
    for (int mi = 0; mi < 2; mi++) {
        f32x4 bvv = *(const f32x4*)(bias + mi * 16 + kg * 4);
        for (int ni = 0; ni < 2; ni++) {
            int slot = (wn * 2 + ni) * 2 + mi;
            f32x4 v = acc[mi][ni] + bvv;
            *(f32x4*)(dst + base + slot * 256 + lane * 4) = v;
        }
    }
}

// ---------------- scores: 256 blocks, each owns a flat 512-elem slice for ALL 16 batches (r11-validated).
__global__ __launch_bounds__(256) void k_scores2(const float* __restrict__ QF, const float* __restrict__ KF,
                                                 float* __restrict__ Sp) {
    __shared__ float Ql[16][520], Kl[16][520];
    int s = blockIdx.x;
    size_t off = (size_t)s * 512;
    int t = threadIdx.x;
    for (int b = 0; b < 16; b++) {
        const float* qs = QF + (size_t)b * DQK + off;
        const float* ks = KF + (size_t)b * DQK + off;
        Ql[b][t]       = qs[t];
        Ql[b][t + 256] = qs[t + 256];
        Kl[b][t]       = ks[t];
        Kl[b][t + 256] = ks[t + 256];
    }
    __syncthreads();
    int p = t >> 1, h = t & 1;
    int b = p >> 3, j = p & 7;
    int hb = b >> 2, wb = b & 3;
    int bp = (j < 4) ? (j * 4 + wb) : (hb * 4 + (j - 4));
    const f32x4* q4 = (const f32x4*)&Ql[b][h * 256];
    const f32x4* k4 = (const f32x4*)&Kl[bp][h * 256];
    f32x4 a4 = (f32x4){0.f, 0.f, 0.f, 0.f};
    for (int i = 0; i < 64; i++) a4 += q4[i] * k4[i];
    float sres = a4[0] + a4[1] + a4[2] + a4[3];
    sres += __shfl_xor(sres, 1);
    if (h == 0) Sp[(size_t)p * 256 + s] = sres;
}

// ---------------- reduce slices + softmax + fold gamma -> M [0..255] + rowsum [256..271]
__global__ void k_softmax2(const float* __restrict__ Sp, const float* __restrict__ gamma,
                           float* __restrict__ Mm) {
    __shared__ float SS[128];
    int t = threadIdx.x;
    const f32x4* s4 = (const f32x4*)(Sp + (size_t)t * 256);
    f32x4 a = (f32x4){0.f, 0.f, 0.f, 0.f};
    for (int i = 0; i < 64; i++) a += s4[i];
    SS[t] = a[0] + a[1] + a[2] + a[3];
    __syncthreads();
    if (t < 16) {
        int b = t, h = b >> 2, w = b & 3;
        float e[8];
        for (int j = 0; j < 8; j++) e[j] = SS[b * 8 + j];
        e[h] = -INFINITY;
        float mx = e[0];
        for (int j = 1; j < 8; j++) mx = fmaxf(mx, e[j]);
        float aa[8], sum = 0.f;
        for (int j = 0; j < 8; j++) { aa[j] = expf(e[j] - mx); sum += aa[j]; }
        float inv = 1.0f / sum;
        float g = gamma[0];
        float row[16];
        for (int c = 0; c < 16; c++) row[c] = 0.f;
        for (int gg = 0; gg < 4; gg++) if (gg != h) row[gg * 4 + w] += aa[gg] * inv;
        for (int gg = 0; gg < 4; gg++) row[h * 4 + gg] += aa[4 + gg] * inv;
        for (int c = 0; c < 16; c++) Mm[b * 16 + c] = row[c] * g;
        Mm[256 + b] = g;
    }
}

// ---------------- mix + transpose + convert -> pre-fragmented Xm; blocks 1024+ pack WvF.
// Xm addr(b,p,c) = b*DV + (p>>4)*4096 + (c>>3)*128 + (p&15)*8 + (c&7).
__global__ __launch_bounds__(256) void k_mix(const float* __restrict__ Mm, const float* __restrict__ x,
                                             const float* __restrict__ wv,
                                             unsigned short* __restrict__ Xm,
                                             unsigned short* __restrict__ WvF) {
    int bid = blockIdx.x;
    int t = threadIdx.x;
    if (bid >= 1024) {                                // 8 pack blocks: wv -> WvF frag layout
        int chunk = (bid - 1024) * 16384;
        for (int i = t; i < 16384; i += 256) {
            int ii = chunk + i;
            int mt = ii >> 12, kt = (ii >> 7) & 31, lr = (ii >> 3) & 15, j = ii & 7;
            WvF[ii] = f2bf(wv[(mt * 16 + lr) * 256 + kt * 8 + j]);
        }
        return;
    }
    __shared__ float Ms[256];
    __shared__ __align__(16) unsigned short T[16][32][40];
    int p0 = (bid & 127) * 32, c0 = (bid >> 7) * 32;
    Ms[t] = Mm[t];

    int c_l = t >> 3, p4 = t & 7;
    f32x4 in4[16];
    for (int bp = 0; bp < 16; bp++)
        in4[bp] = *(const f32x4*)(x + (size_t)bp * DV + (size_t)(c0 + c_l) * HW_ + p0 + p4 * 4);
    __syncthreads();
    for (int b = 0; b < 16; b++) {
        int h = b >> 2, w = b & 3;
        f32x4 acc = (f32x4){0.f, 0.f, 0.f, 0.f};
        #pragma unroll
        for (int g = 0; g < 4; g++) {
            if (g != h) acc += Ms[b * 16 + g * 4 + w] * in4[g * 4 + w];
            acc += Ms[b * 16 + h * 4 + g] * in4[h * 4 + g];
        }
        for (int e = 0; e < 4; e++) T[b][p4 * 4 + e][c_l] = f2bf(acc[e]);
    }
    __syncthreads();
    int p_l = t & 31, co = (t >> 5) & 3, bh = t >> 7;
    int p = p0 + p_l;
    int c = c0 + co * 8;
    size_t dst = (size_t)(p >> 4) * 4096 + (size_t)(c >> 3) * 128 + (p & 15) * 8;
    #pragma unroll
    for (int bi = 0; bi < 8; bi++) {
        int b = bh * 8 + bi;
        u16x8 v = *(const u16x8*)&T[b][p_l][co * 8];
        *(u16x8*)(Xm + (size_t)b * DV + dst) = v;
    }
}

// ---------------- v GEMM + bias + residual: NO-LDS k-loop; LDS-staged coalesced epilogue
// with nontemporal out stores (r11-validated).
__global__ __launch_bounds__(512) void k_gemm_v_res(const unsigned short* __restrict__ WvF,
                                                    const unsigned short* __restrict__ XmF,
                                                    const float* __restrict__ bv,
                                                    const float* __restrict__ MmRs,
                                                    const float* __restrict__ x,
                                                    float* __restrict__ out) {
    __shared__ __align__(16) float LD[256][68];
    int b  = blockIdx.y;
    int n0 = blockIdx.x * 64;
    int t = threadIdx.x;
    int lane = t & 63, wid = t >> 6;
    int wm = wid >> 1, wn = wid & 1;
    int lr = lane & 15, kg = lane >> 4;

    const unsigned short* Bb = XmF + (size_t)b * DV + (size_t)(blockIdx.x * 4 + wn * 2) * 4096 + lane * 8;
    const unsigned short* Ab = WvF + (size_t)(wm * 4) * 4096 + lane * 8;

    bf16x8 bfr[8][2];
    #pragma unroll
    for (int kk = 0; kk < 8; kk++)
        #pragma unroll
        for (int ni = 0; ni < 2; ni++)
            bfr[kk][ni] = *(const bf16x8*)(Bb + (size_t)ni * 4096 + kk * 512);

    f32x4 acc[4][2];
    #pragma unroll
    for (int mi = 0; mi < 4; mi++)
        for (int ni = 0; ni < 2; ni++) acc[mi][ni] = (f32x4){0.f, 0.f, 0.f, 0.f};

    bf16x8 a[4], an[4];
    #pragma unroll
    for (int mi = 0; mi < 4; mi++) a[mi] = *(const bf16x8*)(Ab + (size_t)mi * 4096);
    #pragma unroll
    for (int kk = 0; kk < 8; kk++) {
        if (kk < 7) {
            #pragma unroll
            for (int mi = 0; mi < 4; mi++)
                an[mi] = *(const bf16x8*)(Ab + (size_t)mi * 4096 + (kk + 1) * 512);
        }
        #pragma unroll
        for (int mi = 0; mi < 4; mi++)
            #pragma unroll
            for (int ni = 0; ni < 2; ni++)
                acc[mi][ni] = __builtin_amdgcn_mfma_f32_16x16x32_bf16(a[mi], bfr[kk][ni], acc[mi][ni], 0, 0, 0);
        #pragma unroll
        for (int mi = 0; mi < 4; mi++) a[mi] = an[mi];
    }

    float rs = MmRs[256 + b];
    #pragma unroll
    for (int mi = 0; mi < 4; mi++) {
        int mrow0 = wm * 64 + mi * 16 + kg * 4;
        f32x4 bvv = *(const f32x4*)(bv + mrow0);
        #pragma unroll
        for (int ni = 0; ni < 2; ni++) {
            f32x4 mo = acc[mi][ni] + rs * bvv;
            int ncol = wn * 32 + ni * 16 + lr;
            #pragma unroll
            for (int i = 0; i < 4; i++) LD[mrow0 + i][ncol] = mo[i];
        }
    }
    __syncthreads();
    #pragma unroll
    for (int ps = 0; ps < 8; ps++) {
        int row = wid * 32 + ps * 4 + (lane >> 4);
        int nc  = (lane & 15) * 4;
        f32x4 o = *(const f32x4*)&LD[row][nc];
        size_t g = (size_t)b * DV + (size_t)row * HW_ + n0 + nc;
        f32x4 rr = *(const f32x4*)(x + g);
        __builtin_nontemporal_store(o + rr, (f32x4*)(out + g));
    }
}

extern "C" void kernel_launch(void* const* d_in, const int* in_sizes, int n_in,
                              void* d_out, int out_size, void* d_ws, size_t ws_size,
                              hipStream_t stream) {
    (void)in_sizes; (void)n_in; (void)out_size; (void)ws_size;
    const float* x     = (const float*)d_in[0];
    const float* wq    = (const float*)d_in[1];
    const float* bq    = (const float*)d_in[2];
    const float* wk    = (const float*)d_in[3];
    const float* bk    = (const float*)d_in[4];
    const float* wv    = (const float*)d_in[5];
    const float* bv    = (const float*)d_in[6];
    const float* gamma = (const float*)d_in[7];

    char* ws = (char*)d_ws;
    // ws layout: WvF 131072 | QF 8388608 | KF 8388608 | Mm 1088 | Xm 33554432
    // Sp aliases Xm (consumed by softmax2 before mix writes Xm).
    unsigned short* WvF = (unsigned short*)(ws + 0);
    float*          QF  = (float*)(ws + 131072);
    float*          KF  = (float*)(ws + 8519680);
    float*          Mm  = (float*)(ws + 16908288);
    unsigned short* Xm  = (unsigned short*)(ws + 16910336);   // +33554432 = 50464768 total
    float*          Sp  = (float*)(ws + 16910336);            // aliases Xm
    float*          vo  = (float*)d_out;

    k_gemm_qk    <<<dim3(64, 16), 256, 0, stream>>>(wq, wk, x, bq, bk, QF, KF);
    k_scores2    <<<256, 256, 0, stream>>>(QF, KF, Sp);
    k_softmax2   <<<1, 128, 0, stream>>>(Sp, gamma, Mm);
    k_mix        <<<1032, 256, 0, stream>>>(Mm, x, wv, Xm, WvF);
    k_gemm_v_res <<<dim3(64, 16), 512, 0, stream>>>(WvF, Xm, bv, Mm, x, vo);
}

// Round 14
// 90.735 us; speedup vs baseline: 1.3325x; 1.0552x over previous
//
#include <hip/hip_runtime.h>

#define HW_  4096
#define DQK  131072     // 32*4096 per batch (q or k)
#define DV   1048576    // 256*4096 per batch

using bf16x8 = __attribute__((ext_vector_type(8))) __bf16;
using f32x4  = __attribute__((ext_vector_type(4))) float;
using u16x8  = __attribute__((ext_vector_type(8))) unsigned short;

static __device__ __forceinline__ unsigned short f2bf(float f) {
    union { float f; unsigned u; } v; v.f = f;
    unsigned r = v.u + 0x7FFFu + ((v.u >> 16) & 1u);
    return (unsigned short)(r >> 16);
}
static __device__ __forceinline__ float bf2f(unsigned short h) {
    union { unsigned u; float f; } v; v.u = ((unsigned)h) << 16;
    return v.f;
}

// ---------------- pack weights into MFMA A-fragment layout (r11-validated):
// addr(m,c) = (m>>4)*4096 + (c>>3)*128 + (m&15)*8 + (c&7)
__global__ __launch_bounds__(256) void k_pack(const float* wq, const float* wk, const float* wv,
                                              unsigned short* WhF, unsigned short* WlF, unsigned short* WvF) {
    int idx = blockIdx.x * 256 + threadIdx.x;   // 81920 total
    if (idx < 16384) {
        int i = idx;
        int mt = i >> 12, cg = (i >> 7) & 31, ml = (i >> 3) & 15, cl = i & 7;
        int m = mt * 16 + ml, c = cg * 8 + cl;
        float f = (m < 32) ? wq[m * 256 + c] : wk[(m - 32) * 256 + c];
        unsigned short hi = f2bf(f);
        WhF[i] = hi;
        WlF[i] = f2bf(f - bf2f(hi));
    } else {
        int i = idx - 16384;
        int mt = i >> 12, kt = (i >> 7) & 31, lr = (i >> 3) & 15, j = i & 7;
        int m = mt * 16 + lr, c = kt * 8 + j;
        WvF[i] = f2bf(wv[m * 256 + c]);
    }
}

// ---------------- qk GEMM, split-bf16, NO LDS, no barriers (r11-validated).
// QF/KF stored FLAT: b*DQK + nblk*2048 + slot*256 + lane*4 + i.
__global__ __launch_bounds__(256) void k_gemm_qk(const unsigned short* __restrict__ WhF,
                                                 const unsigned short* __restrict__ WlF,
                                                 const float* __restrict__ x,
                                                 const float* __restrict__ bq, const float* __restrict__ bk,
                                                 float* __restrict__ QF, float* __restrict__ KF) {
    int b  = blockIdx.y;
    int n0 = blockIdx.x * 64;
    int t = threadIdx.x;
    int lane = t & 63, wid = t >> 6;
    int wm = wid & 1, wn = wid >> 1;
    int lr = lane & 15, kg = lane >> 4;

    const float* xb = x + (size_t)b * DV;
    const unsigned short* Ah0 = WhF + (size_t)(wm * 2) * 4096 + lane * 8;
    const unsigned short* Al0 = WlF + (size_t)(wm * 2) * 4096 + lane * 8;

    f32x4 acc[2][2];
    for (int mi = 0; mi < 2; mi++)
        for (int ni = 0; ni < 2; ni++) acc[mi][ni] = (f32x4){0.f, 0.f, 0.f, 0.f};

    for (int kk = 0; kk < 8; kk++) {
        bf16x8 ah[2], al[2];
        for (int mi = 0; mi < 2; mi++) {
            ah[mi] = *(const bf16x8*)(Ah0 + (size_t)mi * 4096 + kk * 512);
            al[mi] = *(const bf16x8*)(Al0 + (size_t)mi * 4096 + kk * 512);
        }
        bf16x8 bh[2], bl[2];
        int cbase = kk * 32 + kg * 8;
        for (int ni = 0; ni < 2; ni++) {
            const float* xp = xb + (size_t)cbase * HW_ + n0 + wn * 32 + ni * 16 + lr;
            #pragma unroll
            for (int j = 0; j < 8; j++) {
                float v = xp[(size_t)j * HW_];
                __bf16 h = (__bf16)v;
                bh[ni][j] = h;
                bl[ni][j] = (__bf16)(v - (float)h);
            }
        }
        for (int mi = 0; mi < 2; mi++)
            for (int ni = 0; ni < 2; ni++) {
                acc[mi][ni] = __builtin_amdgcn_mfma_f32_16x16x32_bf16(ah[mi], bh[ni], acc[mi][ni], 0, 0, 0);
                acc[mi][ni] = __builtin_amdgcn_mfma_f32_16x16x32_bf16(ah[mi], bl[ni], acc[mi][ni], 0, 0, 0);
                acc[mi][ni] = __builtin_amdgcn_mfma_f32_16x16x32_bf16(al[mi], bh[ni], acc[mi][ni], 0, 0, 0);
            }
    }

    float* dst = (wm == 0) ? QF : KF;
    const float* bias = (wm == 0) ? bq : bk;
    size_t base = (size_t)b * DQK + (size_t)blockIdx.x * 2048;
    for (int mi = 0; mi < 2; mi++) {
        f32x4 bvv = *(const f32x4*)(bias + mi * 16 + kg * 4);
        for (int ni = 0; ni < 2; ni++) {
            int slot = (wn * 2 + ni) * 2 + mi;
            f32x4 v = acc[mi][ni] + bvv;
            *(f32x4*)(dst + base + slot * 256 + lane * 4) = v;
        }
    }
}

// ---------------- scores: 256 blocks, each owns a flat 512-elem slice for ALL 16 batches
// (r11-validated). Sp written into d_out scratch (overwritten later by v_res).
__global__ __launch_bounds__(256) void k_scores2(const float* __restrict__ QF, const float* __restrict__ KF,
                                                 float* __restrict__ Sp) {
    __shared__ float Ql[16][520], Kl[16][520];
    int s = blockIdx.x;
    size_t off = (size_t)s * 512;
    int t = threadIdx.x;
    for (int b = 0; b < 16; b++) {
        const float* qs = QF + (size_t)b * DQK + off;
        const float* ks = KF + (size_t)b * DQK + off;
        Ql[b][t]       = qs[t];
        Ql[b][t + 256] = qs[t + 256];
        Kl[b][t]       = ks[t];
        Kl[b][t + 256] = ks[t + 256];
    }
    __syncthreads();
    int p = t >> 1, h = t & 1;
    int b = p >> 3, j = p & 7;
    int hb = b >> 2, wb = b & 3;
    int bp = (j < 4) ? (j * 4 + wb) : (hb * 4 + (j - 4));
    const f32x4* q4 = (const f32x4*)&Ql[b][h * 256];
    const f32x4* k4 = (const f32x4*)&Kl[bp][h * 256];
    f32x4 a4 = (f32x4){0.f, 0.f, 0.f, 0.f};
    for (int i = 0; i < 64; i++) a4 += q4[i] * k4[i];
    float sres = a4[0] + a4[1] + a4[2] + a4[3];
    sres += __shfl_xor(sres, 1);
    if (h == 0) Sp[(size_t)p * 256 + s] = sres;   // layout [pair][slice]
}

// ---------------- mix + in-block softmax + transpose + convert -> pre-fragmented Xm.
// Every block recomputes the 16x16 M (with gamma folded) from Sp (L2-hot, 128 KB);
// softmax compute overlaps the in-flight x loads. Xm layout as r11.
__global__ __launch_bounds__(256) void k_mix(const float* __restrict__ Sp, const float* __restrict__ gamma,
                                             const float* __restrict__ x,
                                             unsigned short* __restrict__ Xm) {
    __shared__ float Ms[256];
    __shared__ float SSl[128];
    __shared__ __align__(16) unsigned short T[16][32][40];
    int t = threadIdx.x;
    int p0 = blockIdx.x * 32, c0 = blockIdx.y * 32;

    // x loads first (16 independent f32x4 in flight)
    int c_l = t >> 3, p4 = t & 7;
    f32x4 in4[16];
    for (int bp = 0; bp < 16; bp++)
        in4[bp] = *(const f32x4*)(x + (size_t)bp * DV + (size_t)(c0 + c_l) * HW_ + p0 + p4 * 4);

    // softmax recompute (overlaps x-load latency)
    if (t < 128) {
        const f32x4* s4 = (const f32x4*)(Sp + (size_t)t * 256);
        f32x4 a = (f32x4){0.f, 0.f, 0.f, 0.f};
        for (int i = 0; i < 64; i++) a += s4[i];
        SSl[t] = a[0] + a[1] + a[2] + a[3];
    }
    __syncthreads();
    if (t < 16) {
        int b = t, h = b >> 2, w = b & 3;
        float e[8];
        for (int j = 0; j < 8; j++) e[j] = SSl[b * 8 + j];
        e[h] = -INFINITY;
        float mx = e[0];
        for (int j = 1; j < 8; j++) mx = fmaxf(mx, e[j]);
        float aa[8], sum = 0.f;
        for (int j = 0; j < 8; j++) { aa[j] = expf(e[j] - mx); sum += aa[j]; }
        float inv = 1.0f / sum;
        float g = gamma[0];
        float row[16];
        for (int c = 0; c < 16; c++) row[c] = 0.f;
        for (int gg = 0; gg < 4; gg++) if (gg != h) row[gg * 4 + w] += aa[gg] * inv;
        for (int gg = 0; gg < 4; gg++) row[h * 4 + gg] += aa[4 + gg] * inv;
        for (int c = 0; c < 16; c++) Ms[b * 16 + c] = row[c] * g;
    }
    __syncthreads();

    for (int b = 0; b < 16; b++) {
        int h = b >> 2, w = b & 3;
        f32x4 acc = (f32x4){0.f, 0.f, 0.f, 0.f};
        #pragma unroll
        for (int g = 0; g < 4; g++) {
            if (g != h) acc += Ms[b * 16 + g * 4 + w] * in4[g * 4 + w];
            acc += Ms[b * 16 + h * 4 + g] * in4[h * 4 + g];
        }
        for (int e = 0; e < 4; e++) T[b][p4 * 4 + e][c_l] = f2bf(acc[e]);
    }
    __syncthreads();
    int p_l = t & 31, co = (t >> 5) & 3, bh = t >> 7;
    int p = p0 + p_l;
    int c = c0 + co * 8;
    size_t dst = (size_t)(p >> 4) * 4096 + (size_t)(c >> 3) * 128 + (p & 15) * 8;
    #pragma unroll
    for (int bi = 0; bi < 8; bi++) {
        int b = bh * 8 + bi;
        u16x8 v = *(const u16x8*)&T[b][p_l][co * 8];
        *(u16x8*)(Xm + (size_t)b * DV + dst) = v;
    }
}

// ---------------- v GEMM + bias + residual: NO-LDS k-loop; LDS-staged coalesced epilogue
// with nontemporal out stores (r11-validated). Row-sum of M is identically gamma.
__global__ __launch_bounds__(512) void k_gemm_v_res(const unsigned short* __restrict__ WvF,
                                                    const unsigned short* __restrict__ XmF,
                                                    const float* __restrict__ bv,
                                                    const float* __restrict__ gamma,
                                                    const float* __restrict__ x,
                                                    float* __restrict__ out) {
    __shared__ __align__(16) float LD[256][68];
    int b  = blockIdx.y;
    int n0 = blockIdx.x * 64;
    int t = threadIdx.x;
    int lane = t & 63, wid = t >> 6;
    int wm = wid >> 1, wn = wid & 1;
    int lr = lane & 15, kg = lane >> 4;

    const unsigned short* Bb = XmF + (size_t)b * DV + (size_t)(blockIdx.x * 4 + wn * 2) * 4096 + lane * 8;
    const unsigned short* Ab = WvF + (size_t)(wm * 4) * 4096 + lane * 8;

    bf16x8 bfr[8][2];
    #pragma unroll
    for (int kk = 0; kk < 8; kk++)
        #pragma unroll
        for (int ni = 0; ni < 2; ni++)
            bfr[kk][ni] = *(const bf16x8*)(Bb + (size_t)ni * 4096 + kk * 512);

    f32x4 acc[4][2];
    #pragma unroll
    for (int mi = 0; mi < 4; mi++)
        for (int ni = 0; ni < 2; ni++) acc[mi][ni] = (f32x4){0.f, 0.f, 0.f, 0.f};

    bf16x8 a[4], an[4];
    #pragma unroll
    for (int mi = 0; mi < 4; mi++) a[mi] = *(const bf16x8*)(Ab + (size_t)mi * 4096);
    #pragma unroll
    for (int kk = 0; kk < 8; kk++) {
        if (kk < 7) {
            #pragma unroll
            for (int mi = 0; mi < 4; mi++)
                an[mi] = *(const bf16x8*)(Ab + (size_t)mi * 4096 + (kk + 1) * 512);
        }
        #pragma unroll
        for (int mi = 0; mi < 4; mi++)
            #pragma unroll
            for (int ni = 0; ni < 2; ni++)
                acc[mi][ni] = __builtin_amdgcn_mfma_f32_16x16x32_bf16(a[mi], bfr[kk][ni], acc[mi][ni], 0, 0, 0);
        #pragma unroll
        for (int mi = 0; mi < 4; mi++) a[mi] = an[mi];
    }

    float rs = gamma[0];                       // row-sum of gamma-folded softmax == gamma
    #pragma unroll
    for (int mi = 0; mi < 4; mi++) {
        int mrow0 = wm * 64 + mi * 16 + kg * 4;
        f32x4 bvv = *(const f32x4*)(bv + mrow0);
        #pragma unroll
        for (int ni = 0; ni < 2; ni++) {
            f32x4 mo = acc[mi][ni] + rs * bvv;
            int ncol = wn * 32 + ni * 16 + lr;
            #pragma unroll
            for (int i = 0; i < 4; i++) LD[mrow0 + i][ncol] = mo[i];
        }
    }
    __syncthreads();
    #pragma unroll
    for (int ps = 0; ps < 8; ps++) {
        int row = wid * 32 + ps * 4 + (lane >> 4);
        int nc  = (lane & 15) * 4;
        f32x4 o = *(const f32x4*)&LD[row][nc];
        size_t g = (size_t)b * DV + (size_t)row * HW_ + n0 + nc;
        f32x4 rr = *(const f32x4*)(x + g);
        __builtin_nontemporal_store(o + rr, (f32x4*)(out + g));
    }
}

extern "C" void kernel_launch(void* const* d_in, const int* in_sizes, int n_in,
                              void* d_out, int out_size, void* d_ws, size_t ws_size,
                              hipStream_t stream) {
    (void)in_sizes; (void)n_in; (void)out_size; (void)ws_size;
    const float* x     = (const float*)d_in[0];
    const float* wq    = (const float*)d_in[1];
    const float* bq    = (const float*)d_in[2];
    const float* wk    = (const float*)d_in[3];
    const float* bk    = (const float*)d_in[4];
    const float* wv    = (const float*)d_in[5];
    const float* bv    = (const float*)d_in[6];
    const float* gamma = (const float*)d_in[7];

    char* ws = (char*)d_ws;
    // ws layout: WhF 32768 | WlF 32768 | WvF 131072 | QF 8388608 | KF 8388608 | Xm 33554432
    // Sp (128 KB) lives in d_out scratch: written by scores2, read by mix, overwritten by v_res.
    unsigned short* WhF = (unsigned short*)(ws + 0);
    unsigned short* WlF = (unsigned short*)(ws + 32768);
    unsigned short* WvF = (unsigned short*)(ws + 65536);
    float*          QF  = (float*)(ws + 196608);
    float*          KF  = (float*)(ws + 8585216);
    unsigned short* Xm  = (unsigned short*)(ws + 16973824);   // +33554432 = 50528256 total
    float*          Sp  = (float*)d_out;                      // scratch in d_out
    float*          vo  = (float*)d_out;

    k_pack       <<<320, 256, 0, stream>>>(wq, wk, wv, WhF, WlF, WvF);
    k_gemm_qk    <<<dim3(64, 16), 256, 0, stream>>>(WhF, WlF, x, bq, bk, QF, KF);
    k_scores2    <<<256, 256, 0, stream>>>(QF, KF, Sp);
    k_mix        <<<dim3(128, 8), 256, 0, stream>>>(Sp, gamma, x, Xm);
    k_gemm_v_res <<<dim3(64, 16), 512, 0, stream>>>(WvF, Xm, bv, gamma, x, vo);
}

// Round 15
// 86.242 us; speedup vs baseline: 1.4019x; 1.0521x over previous
//
#include <hip/hip_runtime.h>

#define HW_  4096
#define DQK  131072     // 32*4096 per batch (q or k)
#define DV   1048576    // 256*4096 per batch

using bf16x8 = __attribute__((ext_vector_type(8))) __bf16;
using f32x4  = __attribute__((ext_vector_type(4))) float;
using u16x8  = __attribute__((ext_vector_type(8))) unsigned short;

static __device__ __forceinline__ unsigned short f2bf(float f) {
    union { float f; unsigned u; } v; v.f = f;
    unsigned r = v.u + 0x7FFFu + ((v.u >> 16) & 1u);
    return (unsigned short)(r >> 16);
}
static __device__ __forceinline__ float bf2f(unsigned short h) {
    union { unsigned u; float f; } v; v.u = ((unsigned)h) << 16;
    return v.f;
}

// ---------------- pack weights into MFMA A-fragment layout (r11-validated):
// addr(m,c) = (m>>4)*4096 + (c>>3)*128 + (m&15)*8 + (c&7)
__global__ __launch_bounds__(256) void k_pack(const float* wq, const float* wk, const float* wv,
                                              unsigned short* WhF, unsigned short* WlF, unsigned short* WvF) {
    int idx = blockIdx.x * 256 + threadIdx.x;   // 81920 total
    if (idx < 16384) {
        int i = idx;
        int mt = i >> 12, cg = (i >> 7) & 31, ml = (i >> 3) & 15, cl = i & 7;
        int m = mt * 16 + ml, c = cg * 8 + cl;
        float f = (m < 32) ? wq[m * 256 + c] : wk[(m - 32) * 256 + c];
        unsigned short hi = f2bf(f);
        WhF[i] = hi;
        WlF[i] = f2bf(f - bf2f(hi));
    } else {
        int i = idx - 16384;
        int mt = i >> 12, kt = (i >> 7) & 31, lr = (i >> 3) & 15, j = i & 7;
        int m = mt * 16 + lr, c = kt * 8 + j;
        WvF[i] = f2bf(wv[m * 256 + c]);
    }
}

// ---------------- qk GEMM, split-bf16, NO LDS, no barriers; SOFTWARE-PIPELINED B loads.
// Explicit cur/next register arrays force 16 loads in flight; __launch_bounds__(256,4)
// gives the compiler a 128-VGPR budget so it doesn't serialize the loads (r14: VGPR=52!).
// QF/KF stored FLAT: b*DQK + nblk*2048 + slot*256 + lane*4 + i.
__global__ __launch_bounds__(256, 4) void k_gemm_qk(const unsigned short* __restrict__ WhF,
                                                    const unsigned short* __restrict__ WlF,
                                                    const float* __restrict__ x,
                                                    const float* __restrict__ bq, const float* __restrict__ bk,
                                                    float* __restrict__ QF, float* __restrict__ KF) {
    int b  = blockIdx.y;
    int n0 = blockIdx.x * 64;
    int t = threadIdx.x;
    int lane = t & 63, wid = t >> 6;
    int wm = wid & 1, wn = wid >> 1;
    int lr = lane & 15, kg = lane >> 4;

    const float* xcol = x + (size_t)b * DV + n0 + wn * 32 + lr;   // + ni*16 + c*HW_
    const unsigned short* Ah0 = WhF + (size_t)(wm * 2) * 4096 + lane * 8;
    const unsigned short* Al0 = WlF + (size_t)(wm * 2) * 4096 + lane * 8;

    f32x4 acc[2][2];
    #pragma unroll
    for (int mi = 0; mi < 2; mi++)
        #pragma unroll
        for (int ni = 0; ni < 2; ni++) acc[mi][ni] = (f32x4){0.f, 0.f, 0.f, 0.f};

    float vb[2][8], vn[2][8];
    #pragma unroll
    for (int ni = 0; ni < 2; ni++)
        #pragma unroll
        for (int j = 0; j < 8; j++)
            vb[ni][j] = xcol[(size_t)(kg * 8 + j) * HW_ + ni * 16];

    #pragma unroll
    for (int kk = 0; kk < 8; kk++) {
        if (kk < 7) {                      // issue next k-step's 16 loads BEFORE current compute
            #pragma unroll
            for (int ni = 0; ni < 2; ni++)
                #pragma unroll
                for (int j = 0; j < 8; j++)
                    vn[ni][j] = xcol[(size_t)((kk + 1) * 32 + kg * 8 + j) * HW_ + ni * 16];
        }
        bf16x8 ah[2], al[2];
        #pragma unroll
        for (int mi = 0; mi < 2; mi++) {
            ah[mi] = *(const bf16x8*)(Ah0 + (size_t)mi * 4096 + kk * 512);
            al[mi] = *(const bf16x8*)(Al0 + (size_t)mi * 4096 + kk * 512);
        }
        bf16x8 bh[2], bl[2];
        #pragma unroll
        for (int ni = 0; ni < 2; ni++)
            #pragma unroll
            for (int j = 0; j < 8; j++) {
                float v = vb[ni][j];
                __bf16 h = (__bf16)v;
                bh[ni][j] = h;
                bl[ni][j] = (__bf16)(v - (float)h);
            }
        #pragma unroll
        for (int mi = 0; mi < 2; mi++)
            #pragma unroll
            for (int ni = 0; ni < 2; ni++) {
                acc[mi][ni] = __builtin_amdgcn_mfma_f32_16x16x32_bf16(ah[mi], bh[ni], acc[mi][ni], 0, 0, 0);
                acc[mi][ni] = __builtin_amdgcn_mfma_f32_16x16x32_bf16(ah[mi], bl[ni], acc[mi][ni], 0, 0, 0);
                acc[mi][ni] = __builtin_amdgcn_mfma_f32_16x16x32_bf16(al[mi], bh[ni], acc[mi][ni], 0, 0, 0);
            }
        #pragma unroll
        for (int ni = 0; ni < 2; ni++)
            #pragma unroll
            for (int j = 0; j < 8; j++) vb[ni][j] = vn[ni][j];
    }

    float* dst = (wm == 0) ? QF : KF;
    const float* bias = (wm == 0) ? bq : bk;
    size_t base = (size_t)b * DQK + (size_t)blockIdx.x * 2048;
    #pragma unroll
    for (int mi = 0; mi < 2; mi++) {
        f32x4 bvv = *(const f32x4*)(bias + mi * 16 + kg * 4);
        #pragma unroll
        for (int ni = 0; ni < 2; ni++) {
            int slot = (wn * 2 + ni) * 2 + mi;
            f32x4 v = acc[mi][ni] + bvv;
            *(f32x4*)(dst + base + slot * 256 + lane * 4) = v;
        }
    }
}

// ---------------- scores: 256 blocks, each owns a flat 512-elem slice for ALL 16 batches (r11-validated).
__global__ __launch_bounds__(256) void k_scores2(const float* __restrict__ QF, const float* __restrict__ KF,
                                                 float* __restrict__ Sp) {
    __shared__ float Ql[16][520], Kl[16][520];
    int s = blockIdx.x;
    size_t off = (size_t)s * 512;
    int t = threadIdx.x;
    for (int b = 0; b < 16; b++) {
        const float* qs = QF + (size_t)b * DQK + off;
        const float* ks = KF + (size_t)b * DQK + off;
        Ql[b][t]       = qs[t];
        Ql[b][t + 256] = qs[t + 256];
        Kl[b][t]       = ks[t];
        Kl[b][t + 256] = ks[t + 256];
    }
    __syncthreads();
    int p = t >> 1, h = t & 1;
    int b = p >> 3, j = p & 7;
    int hb = b >> 2, wb = b & 3;
    int bp = (j < 4) ? (j * 4 + wb) : (hb * 4 + (j - 4));
    const f32x4* q4 = (const f32x4*)&Ql[b][h * 256];
    const f32x4* k4 = (const f32x4*)&Kl[bp][h * 256];
    f32x4 a4 = (f32x4){0.f, 0.f, 0.f, 0.f};
    for (int i = 0; i < 64; i++) a4 += q4[i] * k4[i];
    float sres = a4[0] + a4[1] + a4[2] + a4[3];
    sres += __shfl_xor(sres, 1);
    if (h == 0) Sp[(size_t)p * 256 + s] = sres;
}

// ---------------- reduce slices + softmax + fold gamma -> M [0..255] + rowsum [256..271]
__global__ void k_softmax2(const float* __restrict__ Sp, const float* __restrict__ gamma,
                           float* __restrict__ Mm) {
    __shared__ float SS[128];
    int t = threadIdx.x;
    const f32x4* s4 = (const f32x4*)(Sp + (size_t)t * 256);
    f32x4 a = (f32x4){0.f, 0.f, 0.f, 0.f};
    for (int i = 0; i < 64; i++) a += s4[i];
    SS[t] = a[0] + a[1] + a[2] + a[3];
    __syncthreads();
    if (t < 16) {
        int b = t, h = b >> 2, w = b & 3;
        float e[8];
        for (int j = 0; j < 8; j++) e[j] = SS[b * 8 + j];
        e[h] = -INFINITY;
        float mx = e[0];
        for (int j = 1; j < 8; j++) mx = fmaxf(mx, e[j]);
        float aa[8], sum = 0.f;
        for (int j = 0; j < 8; j++) { aa[j] = expf(e[j] - mx); sum += aa[j]; }
        float inv = 1.0f / sum;
        float g = gamma[0];
        float row[16];
        for (int c = 0; c < 16; c++) row[c] = 0.f;
        for (int gg = 0; gg < 4; gg++) if (gg != h) row[gg * 4 + w] += aa[gg] * inv;
        for (int gg = 0; gg < 4; gg++) row[h * 4 + gg] += aa[4 + gg] * inv;
        for (int c = 0; c < 16; c++) Mm[b * 16 + c] = row[c] * g;
        Mm[256 + b] = g;
    }
}

// ---------------- mix + transpose + convert -> pre-fragmented Xm (r11-validated).
// Xm addr(b,p,c) = b*DV + (p>>4)*4096 + (c>>3)*128 + (p&15)*8 + (c&7).
__global__ __launch_bounds__(256) void k_mix(const float* __restrict__ Mm, const float* __restrict__ x,
                                             unsigned short* __restrict__ Xm) {
    __shared__ float Ms[256];
    __shared__ __align__(16) unsigned short T[16][32][40];
    int t = threadIdx.x;
    int p0 = blockIdx.x * 32, c0 = blockIdx.y * 32;
    Ms[t] = Mm[t];

    int c_l = t >> 3, p4 = t & 7;
    f32x4 in4[16];
    for (int bp = 0; bp < 16; bp++)
        in4[bp] = *(const f32x4*)(x + (size_t)bp * DV + (size_t)(c0 + c_l) * HW_ + p0 + p4 * 4);
    __syncthreads();
    for (int b = 0; b < 16; b++) {
        int h = b >> 2, w = b & 3;
        f32x4 acc = (f32x4){0.f, 0.f, 0.f, 0.f};
        #pragma unroll
        for (int g = 0; g < 4; g++) {
            if (g != h) acc += Ms[b * 16 + g * 4 + w] * in4[g * 4 + w];
            acc += Ms[b * 16 + h * 4 + g] * in4[h * 4 + g];
        }
        for (int e = 0; e < 4; e++) T[b][p4 * 4 + e][c_l] = f2bf(acc[e]);
    }
    __syncthreads();
    int p_l = t & 31, co = (t >> 5) & 3, bh = t >> 7;
    int p = p0 + p_l;
    int c = c0 + co * 8;
    size_t dst = (size_t)(p >> 4) * 4096 + (size_t)(c >> 3) * 128 + (p & 15) * 8;
    #pragma unroll
    for (int bi = 0; bi < 8; bi++) {
        int b = bh * 8 + bi;
        u16x8 v = *(const u16x8*)&T[b][p_l][co * 8];
        *(u16x8*)(Xm + (size_t)b * DV + dst) = v;
    }
}

// ---------------- v GEMM + bias + residual: NO-LDS k-loop; LDS-staged coalesced epilogue
// with nontemporal out stores (r11-validated).
__global__ __launch_bounds__(512) void k_gemm_v_res(const unsigned short* __restrict__ WvF,
                                                    const unsigned short* __restrict__ XmF,
                                                    const float* __restrict__ bv,
                                                    const float* __restrict__ MmRs,
                                                    const float* __restrict__ x,
                                                    float* __restrict__ out) {
    __shared__ __align__(16) float LD[256][68];
    int b  = blockIdx.y;
    int n0 = blockIdx.x * 64;
    int t = threadIdx.x;
    int lane = t & 63, wid = t >> 6;
    int wm = wid >> 1, wn = wid & 1;
    int lr = lane & 15, kg = lane >> 4;

    const unsigned short* Bb = XmF + (size_t)b * DV + (size_t)(blockIdx.x * 4 + wn * 2) * 4096 + lane * 8;
    const unsigned short* Ab = WvF + (size_t)(wm * 4) * 4096 + lane * 8;

    bf16x8 bfr[8][2];
    #pragma unroll
    for (int kk = 0; kk < 8; kk++)
        #pragma unroll
        for (int ni = 0; ni < 2; ni++)
            bfr[kk][ni] = *(const bf16x8*)(Bb + (size_t)ni * 4096 + kk * 512);

    f32x4 acc[4][2];
    #pragma unroll
    for (int mi = 0; mi < 4; mi++)
        for (int ni = 0; ni < 2; ni++) acc[mi][ni] = (f32x4){0.f, 0.f, 0.f, 0.f};

    bf16x8 a[4], an[4];
    #pragma unroll
    for (int mi = 0; mi < 4; mi++) a[mi] = *(const bf16x8*)(Ab + (size_t)mi * 4096);
    #pragma unroll
    for (int kk = 0; kk < 8; kk++) {
        if (kk < 7) {
            #pragma unroll
            for (int mi = 0; mi < 4; mi++)
                an[mi] = *(const bf16x8*)(Ab + (size_t)mi * 4096 + (kk + 1) * 512);
        }
        #pragma unroll
        for (int mi = 0; mi < 4; mi++)
            #pragma unroll
            for (int ni = 0; ni < 2; ni++)
                acc[mi][ni] = __builtin_amdgcn_mfma_f32_16x16x32_bf16(a[mi], bfr[kk][ni], acc[mi][ni], 0, 0, 0);
        #pragma unroll
        for (int mi = 0; mi < 4; mi++) a[mi] = an[mi];
    }

    float rs = MmRs[256 + b];
    #pragma unroll
    for (int mi = 0; mi < 4; mi++) {
        int mrow0 = wm * 64 + mi * 16 + kg * 4;
        f32x4 bvv = *(const f32x4*)(bv + mrow0);
        #pragma unroll
        for (int ni = 0; ni < 2; ni++) {
            f32x4 mo = acc[mi][ni] + rs * bvv;
            int ncol = wn * 32 + ni * 16 + lr;
            #pragma unroll
            for (int i = 0; i < 4; i++) LD[mrow0 + i][ncol] = mo[i];
        }
    }
    __syncthreads();
    #pragma unroll
    for (int ps = 0; ps < 8; ps++) {
        int row = wid * 32 + ps * 4 + (lane >> 4);
        int nc  = (lane & 15) * 4;
        f32x4 o = *(const f32x4*)&LD[row][nc];
        size_t g = (size_t)b * DV + (size_t)row * HW_ + n0 + nc;
        f32x4 rr = *(const f32x4*)(x + g);
        __builtin_nontemporal_store(o + rr, (f32x4*)(out + g));
    }
}

extern "C" void kernel_launch(void* const* d_in, const int* in_sizes, int n_in,
                              void* d_out, int out_size, void* d_ws, size_t ws_size,
                              hipStream_t stream) {
    (void)in_sizes; (void)n_in; (void)out_size; (void)ws_size;
    const float* x     = (const float*)d_in[0];
    const float* wq    = (const float*)d_in[1];
    const float* bq    = (const float*)d_in[2];
    const float* wk    = (const float*)d_in[3];
    const float* bk    = (const float*)d_in[4];
    const float* wv    = (const float*)d_in[5];
    const float* bv    = (const float*)d_in[6];
    const float* gamma = (const float*)d_in[7];

    char* ws = (char*)d_ws;
    // ws layout: WhF 32768 | WlF 32768 | WvF 131072 | QF 8388608 | KF 8388608 | Xm 33554432
    // Aliases (lifetime-disjoint): Mm@0 (WhF dead after qk); Sp@Xm-start (dead before mix writes).
    unsigned short* WhF = (unsigned short*)(ws + 0);
    unsigned short* WlF = (unsigned short*)(ws + 32768);
    unsigned short* WvF = (unsigned short*)(ws + 65536);
    float*          QF  = (float*)(ws + 196608);
    float*          KF  = (float*)(ws + 8585216);
    unsigned short* Xm  = (unsigned short*)(ws + 16973824);  // +33554432 = 50528256 total
    float*          Sp  = (float*)(ws + 16973824);           // aliases Xm (dead before mix)
    float*          Mm  = (float*)(ws + 0);                  // aliases WhF (dead by then)
    float*          vo  = (float*)d_out;

    k_pack       <<<320, 256, 0, stream>>>(wq, wk, wv, WhF, WlF, WvF);
    k_gemm_qk    <<<dim3(64, 16), 256, 0, stream>>>(WhF, WlF, x, bq, bk, QF, KF);
    k_scores2    <<<256, 256, 0, stream>>>(QF, KF, Sp);
    k_softmax2   <<<1, 128, 0, stream>>>(Sp, gamma, Mm);
    k_mix        <<<dim3(128, 8), 256, 0, stream>>>(Mm, x, Xm);
    k_gemm_v_res <<<dim3(64, 16), 512, 0, stream>>>(WvF, Xm, bv, Mm, x, vo);
}